// Round 1
// baseline (222.773 us; speedup 1.0000x reference)
//
#include <hip/hip_runtime.h>
#include <math.h>

#define N_CELLS 65536
#define NH 7
#define NV 4
#define E_IN 16
#define E_OUT 16
#define N_OFF 4
#define N_SIG 4
#define NB 2          // batch
#define NK (N_OFF * N_SIG)   // 16 combined (o,s)

#define CPB 32        // cells per block
#define THREADS 256
#define ND_STRIDE 113 // 16*7=112 padded to 113 (odd -> conflict-free across cells)

__global__ __launch_bounds__(THREADS, 2) void mge_kernel(
    const float* __restrict__ x,
    const float* __restrict__ coords,
    const float* __restrict__ sigma,
    const float* __restrict__ dist_offsets,
    const float* __restrict__ W,
    const float* __restrict__ b_out,
    const int*   __restrict__ adjc,
    const int*   __restrict__ nh_mask,
    float* __restrict__ out)
{
    __shared__ int   adj_lds[CPB][NH];
    __shared__ float d_lds[CPB][NH];
    __shared__ float m_lds[CPB][NH];
    __shared__ float nd_lds[CPB][ND_STRIDE];

    const int t = threadIdx.x;
    const int base = blockIdx.x * CPB;

    // ---------------- Phase 1a: gather adjacency, compute polar distances ----
    if (t < CPB * NH) {
        const int cl = t / NH;
        const int h  = t % NH;
        const int n  = base + cl;
        const int a  = adjc[n * NH + h];
        const int m  = nh_mask[n * NH + h];
        adj_lds[cl][h] = a;
        const float lat_c = coords[n];
        const float lon_c = coords[N_CELLS + n];
        const float lat_n = coords[a];
        const float lon_n = coords[N_CELLS + a];
        float cosd = sinf(lat_c) * sinf(lat_n) +
                     cosf(lat_c) * cosf(lat_n) * cosf(lon_n - lon_c);
        cosd = fminf(fmaxf(cosd, -1.0f + 1e-7f), 1.0f - 1e-7f);
        d_lds[cl][h] = acosf(cosd);
        m_lds[cl][h] = (float)m;
    }
    __syncthreads();

    // ---------------- Phase 1b: normalized nd weights ------------------------
    // tasks: (cell, k) with k = o*N_SIG + s ; normalize over h per (cell,k)
    for (int task = t; task < CPB * NK; task += THREADS) {
        const int cl = task / NK;
        const int k  = task % NK;
        const int o  = k / N_SIG;
        const int s  = k % N_SIG;
        const float off     = dist_offsets[o];
        const float inv_sig = 1.0f / sigma[s];
        float raw[NH];
        float sum = 0.0f;
        #pragma unroll
        for (int h = 0; h < NH; ++h) {
            const float df = (d_lds[cl][h] - off) * inv_sig;
            const float e  = __expf(-0.5f * df * df) * m_lds[cl][h];
            raw[h] = e;
            sum += e;
        }
        const float inv = 1.0f / (sum + 1e-8f);
        #pragma unroll
        for (int h = 0; h < NH; ++h)
            nd_lds[cl][k * NH + h] = raw[h] * inv;
    }
    __syncthreads();

    // ---------------- Phase 2: per-(cell,b,v) thread, full contraction -------
    const int cl = t >> 3;
    const int r  = t & 7;
    const int b  = r >> 2;
    const int v  = r & 3;
    const int n  = base + cl;

    // gather the 7 neighbor rows of x into registers (7 x 16 f32)
    float xr[NH][E_IN];
    #pragma unroll
    for (int h = 0; h < NH; ++h) {
        const int a = adj_lds[cl][h];
        const float4* p = (const float4*)(x + ((((size_t)b * N_CELLS + a) * NV + v) << 4));
        const float4 q0 = p[0], q1 = p[1], q2 = p[2], q3 = p[3];
        xr[h][0]=q0.x;  xr[h][1]=q0.y;  xr[h][2]=q0.z;  xr[h][3]=q0.w;
        xr[h][4]=q1.x;  xr[h][5]=q1.y;  xr[h][6]=q1.z;  xr[h][7]=q1.w;
        xr[h][8]=q2.x;  xr[h][9]=q2.y;  xr[h][10]=q2.z; xr[h][11]=q2.w;
        xr[h][12]=q3.x; xr[h][13]=q3.y; xr[h][14]=q3.z; xr[h][15]=q3.w;
    }

    float acc[E_OUT];
    #pragma unroll
    for (int f = 0; f < E_OUT; ++f) acc[f] = b_out[f];

    #pragma unroll 1
    for (int k = 0; k < NK; ++k) {
        float nds[NH];
        #pragma unroll
        for (int h = 0; h < NH; ++h) nds[h] = nd_lds[cl][k * NH + h];

        float agg[E_IN];
        #pragma unroll
        for (int e = 0; e < E_IN; ++e) {
            float a0 = 0.0f;
            #pragma unroll
            for (int h = 0; h < NH; ++h) a0 += nds[h] * xr[h][e];
            agg[e] = a0;
        }

        const float* wk = W + k * (E_IN * E_OUT);   // W[o][s][e][f]
        #pragma unroll
        for (int e = 0; e < E_IN; ++e) {
            #pragma unroll
            for (int f = 0; f < E_OUT; ++f)
                acc[f] += agg[e] * wk[e * E_OUT + f];
        }
    }

    float4* po = (float4*)(out + ((((size_t)b * N_CELLS + n) * NV + v) << 4));
    po[0] = make_float4(acc[0],  acc[1],  acc[2],  acc[3]);
    po[1] = make_float4(acc[4],  acc[5],  acc[6],  acc[7]);
    po[2] = make_float4(acc[8],  acc[9],  acc[10], acc[11]);
    po[3] = make_float4(acc[12], acc[13], acc[14], acc[15]);
}

extern "C" void kernel_launch(void* const* d_in, const int* in_sizes, int n_in,
                              void* d_out, int out_size, void* d_ws, size_t ws_size,
                              hipStream_t stream) {
    const float* x            = (const float*)d_in[0];
    const float* coords       = (const float*)d_in[1];
    const float* sigma        = (const float*)d_in[2];
    const float* dist_offsets = (const float*)d_in[3];
    const float* W            = (const float*)d_in[4];
    const float* b_out        = (const float*)d_in[5];
    const int*   adjc         = (const int*)d_in[6];
    const int*   nh_mask      = (const int*)d_in[7];
    float* out = (float*)d_out;

    dim3 grid(N_CELLS / CPB);
    mge_kernel<<<grid, THREADS, 0, stream>>>(x, coords, sigma, dist_offsets, W,
                                             b_out, adjc, nh_mask, out);
}

// Round 2
// 70.654 us; speedup vs baseline: 3.1530x; 3.1530x over previous
//
#include <hip/hip_runtime.h>
#include <hip/hip_bf16.h>
#include <math.h>

#define N_CELLS 65536
#define NH 7
#define NV 4
#define E_IN 16
#define E_OUT 16
#define N_OFF 4
#define N_SIG 4
#define NB 2
#define NK 16            // N_OFF * N_SIG

#define CPB 32           // cells per block (4 waves x 4 pairs x 2 cells)
#define THREADS 256
#define PAIRS 4          // cell-pairs per wave

typedef __attribute__((ext_vector_type(8))) short bf16x8;
typedef __attribute__((ext_vector_type(4))) float f32x4;

static __device__ __forceinline__ short f2bf(float f) {
    union { float f; unsigned u; } a; a.f = f;
    unsigned u = a.u;
    u += 0x7fff + ((u >> 16) & 1);   // round-nearest-even
    return (short)(u >> 16);
}

__global__ __launch_bounds__(THREADS, 2) void mge_kernel(
    const float* __restrict__ x,
    const float* __restrict__ coords,
    const float* __restrict__ sigma,
    const float* __restrict__ dist_offsets,
    const float* __restrict__ W,
    const float* __restrict__ b_out,
    const int*   __restrict__ adjc,
    const int*   __restrict__ nh_mask,
    float* __restrict__ out)
{
    __shared__ float w_lds[NK * E_IN * E_OUT];     // 4096 f32 = 16 KB
    __shared__ float nd_lds[CPB][NK][NH];          // 14336 B
    __shared__ int   adj_lds[CPB][NH];
    __shared__ float d_lds[CPB][NH];
    __shared__ float m_lds[CPB][NH];

    const int t = threadIdx.x;
    const int base = blockIdx.x * CPB;

    // ---- stage W (f32) into LDS, coalesced float4 ----
    {
        const float4* src = (const float4*)W;
        float4* dst = (float4*)w_lds;
        #pragma unroll
        for (int i = 0; i < 4; ++i) dst[i * THREADS + t] = src[i * THREADS + t];
    }

    // ---- distances: 32 cells x 7 neighbors = 224 tasks ----
    if (t < CPB * NH) {
        const int cl = t / NH;
        const int h  = t % NH;
        const int n  = base + cl;
        const int a  = adjc[n * NH + h];
        const int m  = nh_mask[n * NH + h];
        adj_lds[cl][h] = a;
        const float lat_c = coords[n];
        const float lon_c = coords[N_CELLS + n];
        const float lat_n = coords[a];
        const float lon_n = coords[N_CELLS + a];
        float cosd = sinf(lat_c) * sinf(lat_n) +
                     cosf(lat_c) * cosf(lat_n) * cosf(lon_n - lon_c);
        cosd = fminf(fmaxf(cosd, -1.0f + 1e-7f), 1.0f - 1e-7f);
        d_lds[cl][h] = acosf(cosd);
        m_lds[cl][h] = (float)m;
    }
    __syncthreads();

    // ---- nd weights: 32 cells x 16 (o,s) = 512 tasks, 2/thread ----
    #pragma unroll
    for (int it = 0; it < 2; ++it) {
        const int task = it * THREADS + t;
        const int cl = task >> 4;
        const int k  = task & 15;          // k = o*N_SIG + s  (W's (o,s) order)
        const int o  = k >> 2;
        const int s  = k & 3;
        const float off     = dist_offsets[o];
        const float inv_sig = 1.0f / sigma[s];
        float raw[NH];
        float sum = 0.0f;
        #pragma unroll
        for (int h = 0; h < NH; ++h) {
            const float df = (d_lds[cl][h] - off) * inv_sig;
            const float e  = __expf(-0.5f * df * df) * m_lds[cl][h];
            raw[h] = e;
            sum += e;
        }
        const float inv = 1.0f / (sum + 1e-8f);
        #pragma unroll
        for (int h = 0; h < NH; ++h)
            nd_lds[cl][k][h] = raw[h] * inv;
    }

    // ---- per-lane B fragments from W (once per block; w_lds ready) ----
    const int lane = t & 63;
    const int wv   = t >> 6;
    const int col  = lane & 15;        // f  (B col / D col / A row index)
    const int grp  = lane >> 4;        // lane group 0..3

    bf16x8 bfrag[8];
    #pragma unroll
    for (int st = 0; st < 8; ++st) {
        bf16x8 bb;
        #pragma unroll
        for (int j = 0; j < 8; ++j) {
            const int kk = st * 32 + grp * 8 + j;   // flat K index = k_os*16 + e
            bb[j] = f2bf(w_lds[kk * E_OUT + col]);
        }
        bfrag[st] = bb;
    }
    const float bias = b_out[col];
    __syncthreads();

    // ---- main: 2 cells per wave-MFMA-tile, 4 pairs per wave ----
    const int cl_in_pair = (lane & 15) >> 3;   // which cell of the pair
    const int bv = lane & 7;
    const int b  = bv >> 2;
    const int v  = bv & 3;
    const int e0 = (grp & 1) * 8;              // which e-half this lane aggregates
    const int kos_off = grp >> 1;              // k_os parity for this lane

    #pragma unroll 1
    for (int p = 0; p < PAIRS; ++p) {
        const int c0 = wv * 8 + p * 2;         // local pair base cell
        const int cl = c0 + cl_in_pair;

        // gather: 7 neighbor rows, 8 floats each (this lane's e-half)
        float xr[NH][8];
        #pragma unroll
        for (int h = 0; h < NH; ++h) {
            const int a = adj_lds[cl][h];
            const float4* px = (const float4*)(x + ((((size_t)b * N_CELLS + a) * NV + v) << 4) + e0);
            const float4 q0 = px[0], q1 = px[1];
            xr[h][0] = q0.x; xr[h][1] = q0.y; xr[h][2] = q0.z; xr[h][3] = q0.w;
            xr[h][4] = q1.x; xr[h][5] = q1.y; xr[h][6] = q1.z; xr[h][7] = q1.w;
        }

        f32x4 acc = {0.f, 0.f, 0.f, 0.f};
        #pragma unroll
        for (int st = 0; st < 8; ++st) {
            const int k2 = st * 2 + kos_off;   // this lane's k_os for this step
            float nds[NH];
            #pragma unroll
            for (int h = 0; h < NH; ++h) nds[h] = nd_lds[cl][k2][h];

            bf16x8 aa;
            #pragma unroll
            for (int j = 0; j < 8; ++j) {
                float s = 0.0f;
                #pragma unroll
                for (int h = 0; h < NH; ++h) s += nds[h] * xr[h][j];
                aa[j] = f2bf(s);
            }
            acc = __builtin_amdgcn_mfma_f32_16x16x32_bf16(aa, bfrag[st], acc, 0, 0, 0);
        }

        // store: D col = lane&15, row = grp*4 + r
        #pragma unroll
        for (int r = 0; r < 4; ++r) {
            const int rr  = grp * 4 + r;
            const int cs  = rr >> 3;
            const int bvs = rr & 7;
            const int bs  = bvs >> 2;
            const int vs  = bvs & 3;
            const int cell = base + c0 + cs;
            out[((((size_t)bs * N_CELLS + cell) * NV + vs) << 4) + col] = acc[r] + bias;
        }
    }
}

extern "C" void kernel_launch(void* const* d_in, const int* in_sizes, int n_in,
                              void* d_out, int out_size, void* d_ws, size_t ws_size,
                              hipStream_t stream) {
    const float* x            = (const float*)d_in[0];
    const float* coords       = (const float*)d_in[1];
    const float* sigma        = (const float*)d_in[2];
    const float* dist_offsets = (const float*)d_in[3];
    const float* W            = (const float*)d_in[4];
    const float* b_out        = (const float*)d_in[5];
    const int*   adjc         = (const int*)d_in[6];
    const int*   nh_mask      = (const int*)d_in[7];
    float* out = (float*)d_out;

    dim3 grid(N_CELLS / CPB);
    mge_kernel<<<grid, THREADS, 0, stream>>>(x, coords, sigma, dist_offsets, W,
                                             b_out, adjc, nh_mask, out);
}